// Round 5
// baseline (97.605 us; speedup 1.0000x reference)
//
#include <hip/hip_runtime.h>
#include <hip/hip_bf16.h>

// Fused KV-cache append + causal SDPA, flash-attention style, bf16 MFMA.
// B=4 S=128 H=32 D=128 T=2048, start read from input (1024).
// R5: T14 register prefetch (issue next tile's 16 global loads during compute),
//     native __float2bfloat16 converts, sv[] folded into sacc[] in place,
//     __launch_bounds__(256,3) to hold 3 waves/SIMD.

typedef short bf16x8 __attribute__((ext_vector_type(8)));
typedef float f32x4  __attribute__((ext_vector_type(4)));

constexpr int B = 4, S = 128, H = 32, D = 128, T = 2048;
constexpr int QBLK = 64, KVBLK = 64;
constexpr int NW = 4;                       // waves per block
constexpr int NS = 3;                       // KV chunks (3 blocks/CU)
constexpr int KP = D + 8;                   // K_lds padded row (bf16 elems)
constexpr int PP = KVBLK + 8;               // P_lds padded row
constexpr float SCALE = 0.08838834764831845f;  // 1/sqrt(128)
constexpr float MNEG = -1e30f;              // sentinel (NaN-free vs -inf)

__device__ __forceinline__ short f2bf(float f) {
    return (short)__bfloat16_as_ushort(__float2bfloat16(f));
}

// MODE 0: single-pass, writes out directly (fallback if ws too small).
// MODE 1: KV-chunk partials (unnormalized O, m, l) to workspace.
template<int MODE>
__global__ __launch_bounds__(256, 3) void sdpa_kernel(
    const float* __restrict__ qg, const float* __restrict__ kin,
    const float* __restrict__ vin, const float* __restrict__ kc,
    const float* __restrict__ vc, const int* __restrict__ ip,
    float* __restrict__ out, float* __restrict__ wsO, float2* __restrict__ wsML)
{
    __shared__ short K_lds[KVBLK][KP];      // [kv][d]  bf16
    __shared__ short V_lds[D * KVBLK];      // [d][kv]  bf16, XOR-swizzled
    __shared__ short P_lds[NW][16][PP];     // per-wave P tile

    const int start = ip[0];
    const int bh = blockIdx.x;
    const int b  = bh >> 5;                 // H = 32
    const int h  = bh & 31;
    const int q0 = blockIdx.y * QBLK;
    const int z  = (MODE == 1) ? blockIdx.z : 0;
    const int t  = threadIdx.x;
    const int w  = t >> 6;
    const int l  = t & 63;
    const int l16 = l & 15;
    const int lg  = l >> 4;                 // 0..3

    // ---- Q fragments: wave owns rows q0+16w .. q0+16w+15 ----
    const int qrow = q0 + w * 16 + l16;
    const float* qp = qg + (((size_t)b * S + qrow) * H + h) * D;
    bf16x8 qfrag[4];
    #pragma unroll
    for (int ks = 0; ks < 4; ++ks) {
        const float* p = qp + ks * 32 + lg * 8;
        #pragma unroll
        for (int i = 0; i < 8; ++i) qfrag[ks][i] = f2bf(p[i]);
    }

    f32x4 oacc[8];
    #pragma unroll
    for (int n = 0; n < 8; ++n) oacc[n] = {0.f, 0.f, 0.f, 0.f};
    float m[4], ssum[4];
    #pragma unroll
    for (int j = 0; j < 4; ++j) { m[j] = MNEG; ssum[j] = 0.f; }

    const int kv_end = start + q0 + QBLK;               // exclusive, 64-aligned
    const int nt     = (kv_end + KVBLK - 1) / KVBLK;
    int t_lo = 0, t_hi = nt;
    if (MODE == 1) {
        const int ct = (nt + NS - 1) / NS;
        t_lo = z * ct;
        t_hi = min(t_lo + ct, nt);
    }

    // ---- prefetch lane mappings ----
    const int r8  = t >> 5, c = t & 31;     // K: row p*8+r8, float4 chunk c
    const int rb  = t & 15, cb0 = t >> 4;   // V: kv 4-row block rb, d-chunk cb0

    auto kaddr = [&](int j) -> const float4* {
        return (j < start)
            ? (const float4*)(kc  + (((size_t)b * T + j) * H + h) * (size_t)D)
            : (const float4*)(kin + (((size_t)b * S + (j - start)) * H + h) * (size_t)D);
    };
    auto vaddr = [&](int j) -> const float4* {
        return (j < start)
            ? (const float4*)(vc  + (((size_t)b * T + j) * H + h) * (size_t)D)
            : (const float4*)(vin + (((size_t)b * S + (j - start)) * H + h) * (size_t)D);
    };

    float4 pk[8], pv[8];                    // next-tile staging registers
    {
        const int j0 = t_lo * KVBLK;
        #pragma unroll
        for (int p = 0; p < 8; ++p) pk[p] = kaddr(j0 + p * 8 + r8)[c];
        #pragma unroll
        for (int it = 0; it < 2; ++it)
            #pragma unroll
            for (int kk = 0; kk < 4; ++kk)
                pv[it * 4 + kk] = vaddr(j0 + rb * 4 + kk)[cb0 + 16 * it];
    }

    for (int tile = t_lo; tile < t_hi; ++tile) {
        const int j0 = tile * KVBLK;

        // ---- stage K from regs (vmcnt wait is implicit at first use) ----
        #pragma unroll
        for (int p = 0; p < 8; ++p) {
            short4 k4b = { f2bf(pk[p].x), f2bf(pk[p].y), f2bf(pk[p].z), f2bf(pk[p].w) };
            *(short4*)&K_lds[p * 8 + r8][c * 4] = k4b;
        }
        // ---- stage V: 4x4 register transpose, XOR-swizzled short4 writes ----
        #pragma unroll
        for (int it = 0; it < 2; ++it) {
            const int cb = cb0 + 16 * it;
            #pragma unroll
            for (int jj = 0; jj < 4; ++jj) {
                const int d = cb * 4 + jj;
                short4 wv = { f2bf(((const float*)&pv[it * 4 + 0])[jj]),
                              f2bf(((const float*)&pv[it * 4 + 1])[jj]),
                              f2bf(((const float*)&pv[it * 4 + 2])[jj]),
                              f2bf(((const float*)&pv[it * 4 + 3])[jj]) };
                int off = d * (KVBLK * 2) + rb * 8;
                off ^= (d & 7) << 4;
                *(short4*)((char*)V_lds + off) = wv;
            }
        }
        __syncthreads();

        // ---- issue next tile's loads now; they land under the compute ----
        if (tile + 1 < t_hi) {
            const int j0n = (tile + 1) * KVBLK;
            #pragma unroll
            for (int p = 0; p < 8; ++p) pk[p] = kaddr(j0n + p * 8 + r8)[c];
            #pragma unroll
            for (int it = 0; it < 2; ++it)
                #pragma unroll
                for (int kk = 0; kk < 4; ++kk)
                    pv[it * 4 + kk] = vaddr(j0n + rb * 4 + kk)[cb0 + 16 * it];
        }

        // ---- QK^T: 4 N-subtiles of 16 kv cols, K-dim = 128 = 4 steps ----
        f32x4 sacc[4];
        #pragma unroll
        for (int n = 0; n < 4; ++n) sacc[n] = {0.f, 0.f, 0.f, 0.f};
        #pragma unroll
        for (int n = 0; n < 4; ++n) {
            #pragma unroll
            for (int ks = 0; ks < 4; ++ks) {
                bf16x8 bfrag = *(const bf16x8*)&K_lds[n * 16 + l16][ks * 32 + lg * 8];
                sacc[n] = __builtin_amdgcn_mfma_f32_16x16x32_bf16(
                    qfrag[ks], bfrag, sacc[n], 0, 0, 0);
            }
        }

        // ---- scale + causal mask + online softmax (in-place in sacc) ----
        float pmax[4];
        #pragma unroll
        for (int j = 0; j < 4; ++j) pmax[j] = MNEG;
        #pragma unroll
        for (int n = 0; n < 4; ++n) {
            const int kvj = j0 + n * 16 + l16;
            #pragma unroll
            for (int j = 0; j < 4; ++j) {
                const int qi = q0 + w * 16 + lg * 4 + j;
                float s = sacc[n][j] * SCALE;
                if (kvj > start + qi) s = MNEG;
                sacc[n][j] = s;
                pmax[j] = fmaxf(pmax[j], s);
            }
        }
        #pragma unroll
        for (int j = 0; j < 4; ++j) {       // row max across 16-lane group
            float v = pmax[j];
            v = fmaxf(v, __shfl_xor(v, 1));
            v = fmaxf(v, __shfl_xor(v, 2));
            v = fmaxf(v, __shfl_xor(v, 4));
            v = fmaxf(v, __shfl_xor(v, 8));
            pmax[j] = v;
        }
        float corr[4];
        #pragma unroll
        for (int j = 0; j < 4; ++j) {
            float mnew = fmaxf(m[j], pmax[j]);
            corr[j] = __expf(m[j] - mnew);  // MNEG-MNEG=0 -> 1, oacc=0: safe
            m[j] = mnew;
        }
        float tsum[4] = {0.f, 0.f, 0.f, 0.f};
        short pbf[4][4];
        #pragma unroll
        for (int n = 0; n < 4; ++n) {
            #pragma unroll
            for (int j = 0; j < 4; ++j) {
                float p = __expf(sacc[n][j] - m[j]);
                tsum[j] += p;
                pbf[j][n] = f2bf(p);
            }
        }
        #pragma unroll
        for (int j = 0; j < 4; ++j) {       // row sum across 16-lane group
            float v = tsum[j];
            v += __shfl_xor(v, 1);
            v += __shfl_xor(v, 2);
            v += __shfl_xor(v, 4);
            v += __shfl_xor(v, 8);
            ssum[j] = ssum[j] * corr[j] + v;
        }
        #pragma unroll
        for (int n = 0; n < 8; ++n) {
            #pragma unroll
            for (int j = 0; j < 4; ++j) oacc[n][j] *= corr[j];
        }

        // ---- P (D-layout) -> LDS -> A-layout fragments ----
        #pragma unroll
        for (int n = 0; n < 4; ++n) {
            #pragma unroll
            for (int j = 0; j < 4; ++j)
                P_lds[w][lg * 4 + j][n * 16 + l16] = pbf[j][n];
        }
        asm volatile("s_waitcnt lgkmcnt(0)" ::: "memory");
        __builtin_amdgcn_sched_barrier(0);

        // ---- PV: out(16x128) += P(16x64) x V(64x128) ----
        #pragma unroll
        for (int ks = 0; ks < 2; ++ks) {
            bf16x8 afrag = *(const bf16x8*)&P_lds[w][l16][ks * 32 + lg * 8];
            #pragma unroll
            for (int n = 0; n < 8; ++n) {
                int off = (n * 16 + l16) * (KVBLK * 2) + ks * 64 + lg * 16;
                off ^= (l16 & 7) << 4;
                bf16x8 bfrag = *(const bf16x8*)((const char*)V_lds + off);
                oacc[n] = __builtin_amdgcn_mfma_f32_16x16x32_bf16(
                    afrag, bfrag, oacc[n], 0, 0, 0);
            }
        }
        __syncthreads();
    }

    // ---- epilogue ----
    #pragma unroll
    for (int j = 0; j < 4; ++j) {
        const int qi = q0 + w * 16 + lg * 4 + j;
        if (MODE == 0) {
            const float inv = 1.0f / ssum[j];
            float* op = out + ((size_t)b * S + qi) * (size_t)(H * D) + h * D;
            #pragma unroll
            for (int n = 0; n < 8; ++n)
                op[n * 16 + l16] = oacc[n][j] * inv;
        } else {
            float* op = wsO + ((((size_t)z * B + b) * S + qi) * H + h) * (size_t)D;
            #pragma unroll
            for (int n = 0; n < 8; ++n)
                op[n * 16 + l16] = oacc[n][j];
            if (l16 == 0)
                wsML[(((size_t)z * B + b) * S + qi) * H + h] = make_float2(m[j], ssum[j]);
        }
    }
}

__global__ __launch_bounds__(256) void combine_kernel(
    const float* __restrict__ wsO, const float2* __restrict__ wsML,
    float* __restrict__ out)
{
    constexpr int R = B * S * H;            // 16384 rows
    constexpr int TOT = R * D;
    for (int idx = blockIdx.x * 256 + threadIdx.x; idx < TOT;
         idx += gridDim.x * 256) {
        const int row = idx >> 7;           // D = 128
        float2 e[NS];
        float M = MNEG;
        #pragma unroll
        for (int cc = 0; cc < NS; ++cc) {
            e[cc] = wsML[(size_t)cc * R + row];
            M = fmaxf(M, e[cc].x);
        }
        float L = 0.f, val = 0.f;
        #pragma unroll
        for (int cc = 0; cc < NS; ++cc) {
            const float wgt = __expf(e[cc].x - M);
            L   += e[cc].y * wgt;
            val += wsO[(size_t)cc * TOT + idx] * wgt;
        }
        out[idx] = val / L;
    }
}

extern "C" void kernel_launch(void* const* d_in, const int* in_sizes, int n_in,
                              void* d_out, int out_size, void* d_ws, size_t ws_size,
                              hipStream_t stream) {
    const float* q  = (const float*)d_in[0];
    const float* k  = (const float*)d_in[1];
    const float* v  = (const float*)d_in[2];
    const float* kc = (const float*)d_in[3];
    const float* vc = (const float*)d_in[4];
    const int*   ip = (const int*)d_in[5];
    float* out = (float*)d_out;

    const size_t nO  = (size_t)NS * B * S * H * D;
    const size_t nML = (size_t)NS * B * S * H;          // float2 elements
    const size_t need = (nO + 2 * nML) * sizeof(float);

    if (ws_size >= need) {
        float*  wsO  = (float*)d_ws;
        float2* wsML = (float2*)(wsO + nO);
        sdpa_kernel<1><<<dim3(B * H, S / QBLK, NS), 256, 0, stream>>>(
            q, k, v, kc, vc, ip, out, wsO, wsML);
        combine_kernel<<<2048, 256, 0, stream>>>(wsO, wsML, out);
    } else {
        sdpa_kernel<0><<<dim3(B * H, S / QBLK), 256, 0, stream>>>(
            q, k, v, kc, vc, ip, out, nullptr, nullptr);
    }
}

// Round 6
// 60.158 us; speedup vs baseline: 1.6225x; 1.6225x over previous
//
#include <hip/hip_runtime.h>
#include <hip/hip_bf16.h>

// Fused KV-cache append + causal SDPA, flash-attention style, bf16 MFMA.
// B=4 S=128 H=32 D=128 T=2048, start read from input (1024).
// R6: R5's register prefetch, but __launch_bounds__(256,2) — R5's (256,3)
//     capped VGPR at ~170 and spilled the 64 prefetch regs to scratch
//     (WRITE_SIZE 26->49MB, FETCH 82->136MB, VGPR_Count 112->84).

typedef short bf16x8 __attribute__((ext_vector_type(8)));
typedef float f32x4  __attribute__((ext_vector_type(4)));

constexpr int B = 4, S = 128, H = 32, D = 128, T = 2048;
constexpr int QBLK = 64, KVBLK = 64;
constexpr int NW = 4;                       // waves per block
constexpr int NS = 3;                       // KV chunks
constexpr int KP = D + 8;                   // K_lds padded row (bf16 elems)
constexpr int PP = KVBLK + 8;               // P_lds padded row
constexpr float SCALE = 0.08838834764831845f;  // 1/sqrt(128)
constexpr float MNEG = -1e30f;              // sentinel (NaN-free vs -inf)

__device__ __forceinline__ short f2bf(float f) {
    return (short)__bfloat16_as_ushort(__float2bfloat16(f));
}

// MODE 0: single-pass, writes out directly (fallback if ws too small).
// MODE 1: KV-chunk partials (unnormalized O, m, l) to workspace.
template<int MODE>
__global__ __launch_bounds__(256, 2) void sdpa_kernel(
    const float* __restrict__ qg, const float* __restrict__ kin,
    const float* __restrict__ vin, const float* __restrict__ kc,
    const float* __restrict__ vc, const int* __restrict__ ip,
    float* __restrict__ out, float* __restrict__ wsO, float2* __restrict__ wsML)
{
    __shared__ short K_lds[KVBLK][KP];      // [kv][d]  bf16
    __shared__ short V_lds[D * KVBLK];      // [d][kv]  bf16, XOR-swizzled
    __shared__ short P_lds[NW][16][PP];     // per-wave P tile

    const int start = ip[0];
    const int bh = blockIdx.x;
    const int b  = bh >> 5;                 // H = 32
    const int h  = bh & 31;
    const int q0 = blockIdx.y * QBLK;
    const int z  = (MODE == 1) ? blockIdx.z : 0;
    const int t  = threadIdx.x;
    const int w  = t >> 6;
    const int l  = t & 63;
    const int l16 = l & 15;
    const int lg  = l >> 4;                 // 0..3

    // ---- Q fragments: wave owns rows q0+16w .. q0+16w+15 ----
    const int qrow = q0 + w * 16 + l16;
    const float* qp = qg + (((size_t)b * S + qrow) * H + h) * D;
    bf16x8 qfrag[4];
    #pragma unroll
    for (int ks = 0; ks < 4; ++ks) {
        const float* p = qp + ks * 32 + lg * 8;
        #pragma unroll
        for (int i = 0; i < 8; ++i) qfrag[ks][i] = f2bf(p[i]);
    }

    f32x4 oacc[8];
    #pragma unroll
    for (int n = 0; n < 8; ++n) oacc[n] = {0.f, 0.f, 0.f, 0.f};
    float m[4], ssum[4];
    #pragma unroll
    for (int j = 0; j < 4; ++j) { m[j] = MNEG; ssum[j] = 0.f; }

    const int kv_end = start + q0 + QBLK;               // exclusive, 64-aligned
    const int nt     = (kv_end + KVBLK - 1) / KVBLK;
    int t_lo = 0, t_hi = nt;
    if (MODE == 1) {
        const int ct = (nt + NS - 1) / NS;
        t_lo = z * ct;
        t_hi = min(t_lo + ct, nt);
    }

    // ---- prefetch lane mappings ----
    const int r8  = t >> 5, c = t & 31;     // K: row p*8+r8, float4 chunk c
    const int rb  = t & 15, cb0 = t >> 4;   // V: kv 4-row block rb, d-chunk cb0

    auto kaddr = [&](int j) -> const float4* {
        return (j < start)
            ? (const float4*)(kc  + (((size_t)b * T + j) * H + h) * (size_t)D)
            : (const float4*)(kin + (((size_t)b * S + (j - start)) * H + h) * (size_t)D);
    };
    auto vaddr = [&](int j) -> const float4* {
        return (j < start)
            ? (const float4*)(vc  + (((size_t)b * T + j) * H + h) * (size_t)D)
            : (const float4*)(vin + (((size_t)b * S + (j - start)) * H + h) * (size_t)D);
    };

    float4 pk[8], pv[8];                    // next-tile staging registers
    {
        const int j0 = t_lo * KVBLK;
        #pragma unroll
        for (int p = 0; p < 8; ++p) pk[p] = kaddr(j0 + p * 8 + r8)[c];
        #pragma unroll
        for (int it = 0; it < 2; ++it)
            #pragma unroll
            for (int kk = 0; kk < 4; ++kk)
                pv[it * 4 + kk] = vaddr(j0 + rb * 4 + kk)[cb0 + 16 * it];
    }

    for (int tile = t_lo; tile < t_hi; ++tile) {
        const int j0 = tile * KVBLK;

        // ---- stage K from regs (vmcnt wait is implicit at first use) ----
        #pragma unroll
        for (int p = 0; p < 8; ++p) {
            short4 k4b = { f2bf(pk[p].x), f2bf(pk[p].y), f2bf(pk[p].z), f2bf(pk[p].w) };
            *(short4*)&K_lds[p * 8 + r8][c * 4] = k4b;
        }
        // ---- stage V: 4x4 register transpose, XOR-swizzled short4 writes ----
        #pragma unroll
        for (int it = 0; it < 2; ++it) {
            const int cb = cb0 + 16 * it;
            #pragma unroll
            for (int jj = 0; jj < 4; ++jj) {
                const int d = cb * 4 + jj;
                short4 wv = { f2bf(((const float*)&pv[it * 4 + 0])[jj]),
                              f2bf(((const float*)&pv[it * 4 + 1])[jj]),
                              f2bf(((const float*)&pv[it * 4 + 2])[jj]),
                              f2bf(((const float*)&pv[it * 4 + 3])[jj]) };
                int off = d * (KVBLK * 2) + rb * 8;
                off ^= (d & 7) << 4;
                *(short4*)((char*)V_lds + off) = wv;
            }
        }
        __syncthreads();

        // ---- issue next tile's loads now; they land under the compute ----
        if (tile + 1 < t_hi) {
            const int j0n = (tile + 1) * KVBLK;
            #pragma unroll
            for (int p = 0; p < 8; ++p) pk[p] = kaddr(j0n + p * 8 + r8)[c];
            #pragma unroll
            for (int it = 0; it < 2; ++it)
                #pragma unroll
                for (int kk = 0; kk < 4; ++kk)
                    pv[it * 4 + kk] = vaddr(j0n + rb * 4 + kk)[cb0 + 16 * it];
        }

        // ---- QK^T: 4 N-subtiles of 16 kv cols, K-dim = 128 = 4 steps ----
        f32x4 sacc[4];
        #pragma unroll
        for (int n = 0; n < 4; ++n) sacc[n] = {0.f, 0.f, 0.f, 0.f};
        #pragma unroll
        for (int n = 0; n < 4; ++n) {
            #pragma unroll
            for (int ks = 0; ks < 4; ++ks) {
                bf16x8 bfrag = *(const bf16x8*)&K_lds[n * 16 + l16][ks * 32 + lg * 8];
                sacc[n] = __builtin_amdgcn_mfma_f32_16x16x32_bf16(
                    qfrag[ks], bfrag, sacc[n], 0, 0, 0);
            }
        }

        // ---- scale + causal mask + online softmax (in-place in sacc) ----
        float pmax[4];
        #pragma unroll
        for (int j = 0; j < 4; ++j) pmax[j] = MNEG;
        #pragma unroll
        for (int n = 0; n < 4; ++n) {
            const int kvj = j0 + n * 16 + l16;
            #pragma unroll
            for (int j = 0; j < 4; ++j) {
                const int qi = q0 + w * 16 + lg * 4 + j;
                float s = sacc[n][j] * SCALE;
                if (kvj > start + qi) s = MNEG;
                sacc[n][j] = s;
                pmax[j] = fmaxf(pmax[j], s);
            }
        }
        #pragma unroll
        for (int j = 0; j < 4; ++j) {       // row max across 16-lane group
            float v = pmax[j];
            v = fmaxf(v, __shfl_xor(v, 1));
            v = fmaxf(v, __shfl_xor(v, 2));
            v = fmaxf(v, __shfl_xor(v, 4));
            v = fmaxf(v, __shfl_xor(v, 8));
            pmax[j] = v;
        }
        float corr[4];
        #pragma unroll
        for (int j = 0; j < 4; ++j) {
            float mnew = fmaxf(m[j], pmax[j]);
            corr[j] = __expf(m[j] - mnew);  // MNEG-MNEG=0 -> 1, oacc=0: safe
            m[j] = mnew;
        }
        float tsum[4] = {0.f, 0.f, 0.f, 0.f};
        short pbf[4][4];
        #pragma unroll
        for (int n = 0; n < 4; ++n) {
            #pragma unroll
            for (int j = 0; j < 4; ++j) {
                float p = __expf(sacc[n][j] - m[j]);
                tsum[j] += p;
                pbf[j][n] = f2bf(p);
            }
        }
        #pragma unroll
        for (int j = 0; j < 4; ++j) {       // row sum across 16-lane group
            float v = tsum[j];
            v += __shfl_xor(v, 1);
            v += __shfl_xor(v, 2);
            v += __shfl_xor(v, 4);
            v += __shfl_xor(v, 8);
            ssum[j] = ssum[j] * corr[j] + v;
        }
        #pragma unroll
        for (int n = 0; n < 8; ++n) {
            #pragma unroll
            for (int j = 0; j < 4; ++j) oacc[n][j] *= corr[j];
        }

        // ---- P (D-layout) -> LDS -> A-layout fragments ----
        #pragma unroll
        for (int n = 0; n < 4; ++n) {
            #pragma unroll
            for (int j = 0; j < 4; ++j)
                P_lds[w][lg * 4 + j][n * 16 + l16] = pbf[j][n];
        }
        asm volatile("s_waitcnt lgkmcnt(0)" ::: "memory");
        __builtin_amdgcn_sched_barrier(0);

        // ---- PV: out(16x128) += P(16x64) x V(64x128) ----
        #pragma unroll
        for (int ks = 0; ks < 2; ++ks) {
            bf16x8 afrag = *(const bf16x8*)&P_lds[w][l16][ks * 32 + lg * 8];
            #pragma unroll
            for (int n = 0; n < 8; ++n) {
                int off = (n * 16 + l16) * (KVBLK * 2) + ks * 64 + lg * 16;
                off ^= (l16 & 7) << 4;
                bf16x8 bfrag = *(const bf16x8*)((const char*)V_lds + off);
                oacc[n] = __builtin_amdgcn_mfma_f32_16x16x32_bf16(
                    afrag, bfrag, oacc[n], 0, 0, 0);
            }
        }
        __syncthreads();
    }

    // ---- epilogue ----
    #pragma unroll
    for (int j = 0; j < 4; ++j) {
        const int qi = q0 + w * 16 + lg * 4 + j;
        if (MODE == 0) {
            const float inv = 1.0f / ssum[j];
            float* op = out + ((size_t)b * S + qi) * (size_t)(H * D) + h * D;
            #pragma unroll
            for (int n = 0; n < 8; ++n)
                op[n * 16 + l16] = oacc[n][j] * inv;
        } else {
            float* op = wsO + ((((size_t)z * B + b) * S + qi) * H + h) * (size_t)D;
            #pragma unroll
            for (int n = 0; n < 8; ++n)
                op[n * 16 + l16] = oacc[n][j];
            if (l16 == 0)
                wsML[(((size_t)z * B + b) * S + qi) * H + h] = make_float2(m[j], ssum[j]);
        }
    }
}

__global__ __launch_bounds__(256) void combine_kernel(
    const float* __restrict__ wsO, const float2* __restrict__ wsML,
    float* __restrict__ out)
{
    constexpr int R = B * S * H;            // 16384 rows
    constexpr int TOT = R * D;
    for (int idx = blockIdx.x * 256 + threadIdx.x; idx < TOT;
         idx += gridDim.x * 256) {
        const int row = idx >> 7;           // D = 128
        float2 e[NS];
        float M = MNEG;
        #pragma unroll
        for (int cc = 0; cc < NS; ++cc) {
            e[cc] = wsML[(size_t)cc * R + row];
            M = fmaxf(M, e[cc].x);
        }
        float L = 0.f, val = 0.f;
        #pragma unroll
        for (int cc = 0; cc < NS; ++cc) {
            const float wgt = __expf(e[cc].x - M);
            L   += e[cc].y * wgt;
            val += wsO[(size_t)cc * TOT + idx] * wgt;
        }
        out[idx] = val / L;
    }
}

extern "C" void kernel_launch(void* const* d_in, const int* in_sizes, int n_in,
                              void* d_out, int out_size, void* d_ws, size_t ws_size,
                              hipStream_t stream) {
    const float* q  = (const float*)d_in[0];
    const float* k  = (const float*)d_in[1];
    const float* v  = (const float*)d_in[2];
    const float* kc = (const float*)d_in[3];
    const float* vc = (const float*)d_in[4];
    const int*   ip = (const int*)d_in[5];
    float* out = (float*)d_out;

    const size_t nO  = (size_t)NS * B * S * H * D;
    const size_t nML = (size_t)NS * B * S * H;          // float2 elements
    const size_t need = (nO + 2 * nML) * sizeof(float);

    if (ws_size >= need) {
        float*  wsO  = (float*)d_ws;
        float2* wsML = (float2*)(wsO + nO);
        sdpa_kernel<1><<<dim3(B * H, S / QBLK, NS), 256, 0, stream>>>(
            q, k, v, kc, vc, ip, out, wsO, wsML);
        combine_kernel<<<2048, 256, 0, stream>>>(wsO, wsML, out);
    } else {
        sdpa_kernel<0><<<dim3(B * H, S / QBLK), 256, 0, stream>>>(
            q, k, v, kc, vc, ip, out, nullptr, nullptr);
    }
}

// Round 7
// 57.080 us; speedup vs baseline: 1.7100x; 1.0539x over previous
//
#include <hip/hip_runtime.h>
#include <hip/hip_bf16.h>

// Fused KV-cache append + causal SDPA, flash-attention style, bf16 MFMA.
// B=4 S=128 H=32 D=128 T=2048, start read from input (1024).
// R7: swapped QK^T (mfma(K,Q) -> S^T, one q-row per lane) => softmax local
//     reduce + 2 shfl (was 32 shfl); P packed b64 stores; K/P XOR-swizzled
//     linear LDS => 40KB = 4 blocks/CU; NS=4 strided chunks; prefetch kept.

typedef short bf16x8 __attribute__((ext_vector_type(8)));
typedef float f32x4  __attribute__((ext_vector_type(4)));

constexpr int B = 4, S = 128, H = 32, D = 128, T = 2048;
constexpr int QBLK = 64, KVBLK = 64;
constexpr int NW = 4;                       // waves per block
constexpr int NS = 4;                       // KV chunks (4 blocks/CU)
constexpr float SCALE = 0.08838834764831845f;  // 1/sqrt(128)
constexpr float MNEG = -1e30f;              // sentinel (NaN-free vs -inf)

__device__ __forceinline__ short f2bf(float f) {
    return (short)__bfloat16_as_ushort(__float2bfloat16(f));
}

// XOR-swizzled byte offsets: row-major rows of 256B (K) / 128B (V, P)
__device__ __forceinline__ int kswz(int row, int cb) { return row * 256 + (cb ^ ((row & 7) << 4)); }
__device__ __forceinline__ int vswz(int row, int cb) { return row * 128 + (cb ^ ((row & 7) << 4)); }
__device__ __forceinline__ int pswz(int wv, int row, int cb) { return wv * 2048 + row * 128 + (cb ^ ((row & 7) << 4)); }

// MODE 0: single-pass, writes out directly (fallback if ws too small).
// MODE 1: KV-chunk partials (unnormalized O, m, l) to workspace.
template<int MODE>
__global__ __launch_bounds__(256, 2) void sdpa_kernel(
    const float* __restrict__ qg, const float* __restrict__ kin,
    const float* __restrict__ vin, const float* __restrict__ kc,
    const float* __restrict__ vc, const int* __restrict__ ip,
    float* __restrict__ out, float* __restrict__ wsO, float2* __restrict__ wsML)
{
    __shared__ short K_lds[KVBLK * D];      // 16 KB, [kv][d] swizzled
    __shared__ short V_lds[D * KVBLK];      // 16 KB, [d][kv] swizzled
    __shared__ short P_lds[NW * 16 * 64];   //  8 KB, [w][q][kv] swizzled

    const int start = ip[0];
    const int bh = blockIdx.x;
    const int b  = bh >> 5;                 // H = 32
    const int h  = bh & 31;
    const int q0 = blockIdx.y * QBLK;
    const int z  = (MODE == 1) ? blockIdx.z : 0;
    const int t  = threadIdx.x;
    const int w  = t >> 6;
    const int l  = t & 63;
    const int l16 = l & 15;
    const int lg  = l >> 4;                 // 0..3
    const int qi  = q0 + w * 16 + l16;      // this lane's q row (softmax owner)

    // ---- Q fragments: wave owns rows q0+16w .. q0+16w+15 ----
    const float* qp = qg + (((size_t)b * S + qi) * H + h) * D;
    bf16x8 qfrag[4];
    #pragma unroll
    for (int ks = 0; ks < 4; ++ks) {
        const float* p = qp + ks * 32 + lg * 8;
        #pragma unroll
        for (int i = 0; i < 8; ++i) qfrag[ks][i] = f2bf(p[i]);
    }

    f32x4 oacc[8];
    #pragma unroll
    for (int n = 0; n < 8; ++n) oacc[n] = {0.f, 0.f, 0.f, 0.f};
    float m = MNEG, ssum = 0.f;             // per-lane (q = l16) stats

    const int kv_end = start + q0 + QBLK;               // exclusive, 64-aligned
    const int nt     = (kv_end + KVBLK - 1) / KVBLK;
    const int tstep  = (MODE == 1) ? NS : 1;
    const int t0     = (MODE == 1) ? z : 0;             // strided chunking

    // ---- prefetch lane mappings ----
    const int r8  = t >> 5, c = t & 31;     // K: row p*8+r8, float4 chunk c
    const int rb  = t & 15, cb0 = t >> 4;   // V: kv 4-row block rb, d-chunk cb0

    auto kaddr = [&](int j) -> const float4* {
        return (j < start)
            ? (const float4*)(kc  + (((size_t)b * T + j) * H + h) * (size_t)D)
            : (const float4*)(kin + (((size_t)b * S + (j - start)) * H + h) * (size_t)D);
    };
    auto vaddr = [&](int j) -> const float4* {
        return (j < start)
            ? (const float4*)(vc  + (((size_t)b * T + j) * H + h) * (size_t)D)
            : (const float4*)(vin + (((size_t)b * S + (j - start)) * H + h) * (size_t)D);
    };

    float4 pk[8], pv[8];                    // next-tile staging registers
    {
        const int j0 = t0 * KVBLK;
        #pragma unroll
        for (int p = 0; p < 8; ++p) pk[p] = kaddr(j0 + p * 8 + r8)[c];
        #pragma unroll
        for (int it = 0; it < 2; ++it)
            #pragma unroll
            for (int kk = 0; kk < 4; ++kk)
                pv[it * 4 + kk] = vaddr(j0 + rb * 4 + kk)[cb0 + 16 * it];
    }

    for (int tile = t0; tile < nt; tile += tstep) {
        const int j0 = tile * KVBLK;

        // ---- stage K from regs into swizzled LDS ----
        #pragma unroll
        for (int p = 0; p < 8; ++p) {
            short4 k4b = { f2bf(pk[p].x), f2bf(pk[p].y), f2bf(pk[p].z), f2bf(pk[p].w) };
            *(short4*)((char*)K_lds + kswz(p * 8 + r8, c * 8)) = k4b;
        }
        // ---- stage V: 4x4 register transpose, swizzled short4 writes ----
        #pragma unroll
        for (int it = 0; it < 2; ++it) {
            const int cb = cb0 + 16 * it;
            #pragma unroll
            for (int jj = 0; jj < 4; ++jj) {
                const int d = cb * 4 + jj;
                short4 wv = { f2bf(((const float*)&pv[it * 4 + 0])[jj]),
                              f2bf(((const float*)&pv[it * 4 + 1])[jj]),
                              f2bf(((const float*)&pv[it * 4 + 2])[jj]),
                              f2bf(((const float*)&pv[it * 4 + 3])[jj]) };
                *(short4*)((char*)V_lds + vswz(d, rb * 8)) = wv;
            }
        }
        // ---- issue next tile's loads; they fly under barrier + compute ----
        if (tile + tstep < nt) {
            const int j0n = (tile + tstep) * KVBLK;
            #pragma unroll
            for (int p = 0; p < 8; ++p) pk[p] = kaddr(j0n + p * 8 + r8)[c];
            #pragma unroll
            for (int it = 0; it < 2; ++it)
                #pragma unroll
                for (int kk = 0; kk < 4; ++kk)
                    pv[it * 4 + kk] = vaddr(j0n + rb * 4 + kk)[cb0 + 16 * it];
        }
        __syncthreads();

        // ---- QK^T, SWAPPED: S^T_n = K_n * Q^T ----
        // lane l: sacc[n][j] = S[q = l16][kv = j0 + n*16 + lg*4 + j]
        f32x4 sacc[4];
        #pragma unroll
        for (int n = 0; n < 4; ++n) sacc[n] = {0.f, 0.f, 0.f, 0.f};
        #pragma unroll
        for (int n = 0; n < 4; ++n) {
            #pragma unroll
            for (int ks = 0; ks < 4; ++ks) {
                bf16x8 kfrag = *(const bf16x8*)((const char*)K_lds +
                                 kswz(n * 16 + l16, ks * 64 + lg * 16));
                sacc[n] = __builtin_amdgcn_mfma_f32_16x16x32_bf16(
                    kfrag, qfrag[ks], sacc[n], 0, 0, 0);
            }
        }

        // ---- scale + causal mask + online softmax (row-per-lane) ----
        float pmax = MNEG;
        #pragma unroll
        for (int n = 0; n < 4; ++n) {
            #pragma unroll
            for (int j = 0; j < 4; ++j) {
                const int kvj = j0 + n * 16 + lg * 4 + j;
                float s = sacc[n][j] * SCALE;
                if (kvj > start + qi) s = MNEG;
                sacc[n][j] = s;
                pmax = fmaxf(pmax, s);
            }
        }
        pmax = fmaxf(pmax, __shfl_xor(pmax, 16));
        pmax = fmaxf(pmax, __shfl_xor(pmax, 32));
        const float mnew = fmaxf(m, pmax);
        const float corr = __expf(m - mnew);
        m = mnew;

        float tsum = 0.f;
        short4 pq[4];
        #pragma unroll
        for (int n = 0; n < 4; ++n) {
            float p0 = __expf(sacc[n][0] - m);
            float p1 = __expf(sacc[n][1] - m);
            float p2 = __expf(sacc[n][2] - m);
            float p3 = __expf(sacc[n][3] - m);
            tsum += (p0 + p1) + (p2 + p3);
            pq[n] = { f2bf(p0), f2bf(p1), f2bf(p2), f2bf(p3) };
        }
        tsum += __shfl_xor(tsum, 16);
        tsum += __shfl_xor(tsum, 32);
        ssum = ssum * corr + tsum;

        // corr for the O rows this lane accumulates (q = lg*4+j)
        float corrj[4];
        #pragma unroll
        for (int j = 0; j < 4; ++j) corrj[j] = __shfl(corr, lg * 4 + j);
        #pragma unroll
        for (int n = 0; n < 8; ++n) {
            #pragma unroll
            for (int j = 0; j < 4; ++j) oacc[n][j] *= corrj[j];
        }

        // ---- P store: lane-local row, 4x ds_write_b64, swizzled ----
        #pragma unroll
        for (int n = 0; n < 4; ++n)
            *(short4*)((char*)P_lds + pswz(w, l16, n * 32 + lg * 8)) = pq[n];
        asm volatile("s_waitcnt lgkmcnt(0)" ::: "memory");
        __builtin_amdgcn_sched_barrier(0);

        // ---- PV: out(16x128) += P(16x64) x V(64x128) ----
        #pragma unroll
        for (int ks = 0; ks < 2; ++ks) {
            bf16x8 afrag = *(const bf16x8*)((const char*)P_lds +
                             pswz(w, l16, ks * 64 + lg * 16));
            #pragma unroll
            for (int n = 0; n < 8; ++n) {
                bf16x8 bfrag = *(const bf16x8*)((const char*)V_lds +
                                 vswz(n * 16 + l16, ks * 64 + lg * 16));
                oacc[n] = __builtin_amdgcn_mfma_f32_16x16x32_bf16(
                    afrag, bfrag, oacc[n], 0, 0, 0);
            }
        }
        __syncthreads();
    }

    // ---- epilogue ----
    if (MODE == 0) {
        #pragma unroll
        for (int j = 0; j < 4; ++j) {
            const float inv = 1.0f / __shfl(ssum, lg * 4 + j);
            const int qr = q0 + w * 16 + lg * 4 + j;
            float* op = out + ((size_t)b * S + qr) * (size_t)(H * D) + h * D;
            #pragma unroll
            for (int n = 0; n < 8; ++n)
                op[n * 16 + l16] = oacc[n][j] * inv;
        }
    } else {
        #pragma unroll
        for (int j = 0; j < 4; ++j) {
            const int qr = q0 + w * 16 + lg * 4 + j;
            float* op = wsO + ((((size_t)z * B + b) * S + qr) * H + h) * (size_t)D;
            #pragma unroll
            for (int n = 0; n < 8; ++n)
                op[n * 16 + l16] = oacc[n][j];
        }
        if (lg == 0)                         // lanes 0..15 own rows q0+w*16+l16
            wsML[(((size_t)z * B + b) * S + qi) * H + h] = make_float2(m, ssum);
    }
}

__global__ __launch_bounds__(256) void combine_kernel(
    const float* __restrict__ wsO, const float2* __restrict__ wsML,
    float* __restrict__ out)
{
    constexpr int R    = B * S * H;         // 16384 rows
    constexpr int TOT4 = R * D / 4;         // float4 elements
    for (int i4 = blockIdx.x * 256 + threadIdx.x; i4 < TOT4;
         i4 += gridDim.x * 256) {
        const int row = i4 >> 5;            // D/4 = 32 float4 per row
        float2 e[NS];
        float M = MNEG;
        #pragma unroll
        for (int cc = 0; cc < NS; ++cc) {
            e[cc] = wsML[(size_t)cc * R + row];
            M = fmaxf(M, e[cc].x);
        }
        float L = 0.f;
        float v0 = 0.f, v1 = 0.f, v2 = 0.f, v3 = 0.f;
        #pragma unroll
        for (int cc = 0; cc < NS; ++cc) {
            const float wgt = __expf(e[cc].x - M);
            L += e[cc].y * wgt;
            float4 tv = ((const float4*)wsO)[(size_t)cc * TOT4 + i4];
            v0 += tv.x * wgt; v1 += tv.y * wgt; v2 += tv.z * wgt; v3 += tv.w * wgt;
        }
        const float inv = 1.0f / L;
        ((float4*)out)[i4] = make_float4(v0 * inv, v1 * inv, v2 * inv, v3 * inv);
    }
}

extern "C" void kernel_launch(void* const* d_in, const int* in_sizes, int n_in,
                              void* d_out, int out_size, void* d_ws, size_t ws_size,
                              hipStream_t stream) {
    const float* q  = (const float*)d_in[0];
    const float* k  = (const float*)d_in[1];
    const float* v  = (const float*)d_in[2];
    const float* kc = (const float*)d_in[3];
    const float* vc = (const float*)d_in[4];
    const int*   ip = (const int*)d_in[5];
    float* out = (float*)d_out;

    const size_t nO  = (size_t)NS * B * S * H * D;
    const size_t nML = (size_t)NS * B * S * H;          // float2 elements
    const size_t need = (nO + 2 * nML) * sizeof(float);

    if (ws_size >= need) {
        float*  wsO  = (float*)d_ws;
        float2* wsML = (float2*)(wsO + nO);
        sdpa_kernel<1><<<dim3(B * H, S / QBLK, NS), 256, 0, stream>>>(
            q, k, v, kc, vc, ip, out, wsO, wsML);
        combine_kernel<<<2048, 256, 0, stream>>>(wsO, wsML, out);
    } else {
        sdpa_kernel<0><<<dim3(B * H, S / QBLK), 256, 0, stream>>>(
            q, k, v, kc, vc, ip, out, nullptr, nullptr);
    }
}

// Round 8
// 57.000 us; speedup vs baseline: 1.7124x; 1.0014x over previous
//
#include <hip/hip_runtime.h>
#include <hip/hip_bf16.h>

// Fused KV-cache append + causal SDPA, flash-attention style, bf16 MFMA.
// B=4 S=128 H=32 D=128 T=2048, start read from input (1024).
// R8: (1) prefetch pinned with sched_barrier(0) (R7 VGPR=108 proves compiler
//     sank the loads); (2) P redistribution in-register via 16 shfl (drop
//     P_lds, LDS 40->32KB, no lgkmcnt serializer); (3) PV swapped ->
//     O^T accumulation: corr/ssum/normalize lane-local; epilogue transposes
//     through per-wave LDS scratch so global writes stay coalesced.

typedef short bf16x8 __attribute__((ext_vector_type(8)));
typedef float f32x4  __attribute__((ext_vector_type(4)));

constexpr int B = 4, S = 128, H = 32, D = 128, T = 2048;
constexpr int QBLK = 64, KVBLK = 64;
constexpr int NS = 4;                       // KV chunks
constexpr float SCALE = 0.08838834764831845f;  // 1/sqrt(128)
constexpr float MNEG = -1e30f;              // sentinel (NaN-free vs -inf)

__device__ __forceinline__ short f2bf(float f) {
    return (short)__bfloat16_as_ushort(__float2bfloat16(f));
}
__device__ __forceinline__ unsigned pack_bf2(float a, float b) {
    return (unsigned)(unsigned short)__bfloat16_as_ushort(__float2bfloat16(a))
         | ((unsigned)__bfloat16_as_ushort(__float2bfloat16(b)) << 16);
}

// XOR-swizzled byte offsets into 32KB smem: K rows 256B, V rows 128B.
__device__ __forceinline__ int kswz(int row, int cb) { return row * 256 + (cb ^ ((row & 7) << 4)); }
__device__ __forceinline__ int vswz(int row, int cb) { return 16384 + row * 128 + (cb ^ ((row & 7) << 4)); }

// MODE 0: single-pass, writes out directly (fallback if ws too small).
// MODE 1: KV-chunk partials (unnormalized O, m, l) to workspace.
template<int MODE>
__global__ __launch_bounds__(256, 2) void sdpa_kernel(
    const float* __restrict__ qg, const float* __restrict__ kin,
    const float* __restrict__ vin, const float* __restrict__ kc,
    const float* __restrict__ vc, const int* __restrict__ ip,
    float* __restrict__ out, float* __restrict__ wsO, float2* __restrict__ wsML)
{
    __shared__ __align__(16) char smem[32768];   // K 16KB | V 16KB; epilogue scratch

    const int start = ip[0];
    const int bh = blockIdx.x;
    const int b  = bh >> 5;                 // H = 32
    const int h  = bh & 31;
    const int q0 = blockIdx.y * QBLK;
    const int z  = (MODE == 1) ? blockIdx.z : 0;
    const int t  = threadIdx.x;
    const int w  = t >> 6;
    const int l  = t & 63;
    const int l16 = l & 15;
    const int lg  = l >> 4;                 // 0..3
    const int qi  = q0 + w * 16 + l16;      // this lane's q row (stats owner)

    // ---- Q fragments (B-operand of swapped QK): wave rows q0+16w..+15 ----
    const float* qp = qg + (((size_t)b * S + qi) * H + h) * D;
    bf16x8 qfrag[4];
    #pragma unroll
    for (int ks = 0; ks < 4; ++ks) {
        const float* p = qp + ks * 32 + lg * 8;
        #pragma unroll
        for (int i = 0; i < 8; ++i) qfrag[ks][i] = f2bf(p[i]);
    }

    f32x4 oaccT[8];                         // O^T: lane q=l16, d=n*16+lg*4+j
    #pragma unroll
    for (int n = 0; n < 8; ++n) oaccT[n] = {0.f, 0.f, 0.f, 0.f};
    float m = MNEG, ssum = 0.f;             // per-lane (q = l16) stats

    const int kv_end = start + q0 + QBLK;               // exclusive, 64-aligned
    const int nt     = (kv_end + KVBLK - 1) / KVBLK;
    const int tstep  = (MODE == 1) ? NS : 1;
    const int t0     = (MODE == 1) ? z : 0;             // strided chunking

    // ---- staging lane mappings ----
    const int r8  = t >> 5, c = t & 31;     // K: row p*8+r8, float4 chunk c
    const int rb  = t & 15, cb0 = t >> 4;   // V: kv 4-row block rb, d-chunk cb0

    auto kaddr = [&](int j) -> const float4* {
        return (j < start)
            ? (const float4*)(kc  + (((size_t)b * T + j) * H + h) * (size_t)D)
            : (const float4*)(kin + (((size_t)b * S + (j - start)) * H + h) * (size_t)D);
    };
    auto vaddr = [&](int j) -> const float4* {
        return (j < start)
            ? (const float4*)(vc  + (((size_t)b * T + j) * H + h) * (size_t)D)
            : (const float4*)(vin + (((size_t)b * S + (j - start)) * H + h) * (size_t)D);
    };

    float4 pk[8], pv[8];                    // next-tile staging registers
    {
        const int j0 = t0 * KVBLK;
        #pragma unroll
        for (int p = 0; p < 8; ++p) pk[p] = kaddr(j0 + p * 8 + r8)[c];
        #pragma unroll
        for (int it = 0; it < 2; ++it)
            #pragma unroll
            for (int kk = 0; kk < 4; ++kk)
                pv[it * 4 + kk] = vaddr(j0 + rb * 4 + kk)[cb0 + 16 * it];
        __builtin_amdgcn_sched_barrier(0);  // pin issue point
    }

    for (int tile = t0; tile < nt; tile += tstep) {
        const int j0 = tile * KVBLK;

        // ---- stage K from regs into swizzled LDS ----
        #pragma unroll
        for (int p = 0; p < 8; ++p) {
            short4 k4b = { f2bf(pk[p].x), f2bf(pk[p].y), f2bf(pk[p].z), f2bf(pk[p].w) };
            *(short4*)(smem + kswz(p * 8 + r8, c * 8)) = k4b;
        }
        // ---- stage V: 4x4 register transpose, swizzled short4 writes ----
        #pragma unroll
        for (int it = 0; it < 2; ++it) {
            const int cb = cb0 + 16 * it;
            #pragma unroll
            for (int jj = 0; jj < 4; ++jj) {
                const int d = cb * 4 + jj;
                short4 wv = { f2bf(((const float*)&pv[it * 4 + 0])[jj]),
                              f2bf(((const float*)&pv[it * 4 + 1])[jj]),
                              f2bf(((const float*)&pv[it * 4 + 2])[jj]),
                              f2bf(((const float*)&pv[it * 4 + 3])[jj]) };
                *(short4*)(smem + vswz(d, rb * 8)) = wv;
            }
        }
        // ---- issue next tile's loads, pinned here by sched_barrier ----
        if (tile + tstep < nt) {
            const int j0n = (tile + tstep) * KVBLK;
            #pragma unroll
            for (int p = 0; p < 8; ++p) pk[p] = kaddr(j0n + p * 8 + r8)[c];
            #pragma unroll
            for (int it = 0; it < 2; ++it)
                #pragma unroll
                for (int kk = 0; kk < 4; ++kk)
                    pv[it * 4 + kk] = vaddr(j0n + rb * 4 + kk)[cb0 + 16 * it];
        }
        __builtin_amdgcn_sched_barrier(0);  // loads may not sink below this
        __syncthreads();

        // ---- QK^T swapped: sacc[n][j] = S[q=l16][kv = n*16+lg*4+j] ----
        f32x4 sacc[4];
        #pragma unroll
        for (int n = 0; n < 4; ++n) sacc[n] = {0.f, 0.f, 0.f, 0.f};
        #pragma unroll
        for (int n = 0; n < 4; ++n) {
            #pragma unroll
            for (int ks = 0; ks < 4; ++ks) {
                bf16x8 kfrag = *(const bf16x8*)(smem + kswz(n * 16 + l16, ks * 64 + lg * 16));
                sacc[n] = __builtin_amdgcn_mfma_f32_16x16x32_bf16(
                    kfrag, qfrag[ks], sacc[n], 0, 0, 0);
            }
        }

        // ---- scale + causal mask + online softmax (row-per-lane) ----
        float pmax = MNEG;
        #pragma unroll
        for (int n = 0; n < 4; ++n) {
            #pragma unroll
            for (int j = 0; j < 4; ++j) {
                const int kvj = j0 + n * 16 + lg * 4 + j;
                float s = sacc[n][j] * SCALE;
                if (kvj > start + qi) s = MNEG;
                sacc[n][j] = s;
                pmax = fmaxf(pmax, s);
            }
        }
        pmax = fmaxf(pmax, __shfl_xor(pmax, 16));
        pmax = fmaxf(pmax, __shfl_xor(pmax, 32));
        const float mnew = fmaxf(m, pmax);
        const float corr = __expf(m - mnew);
        m = mnew;

        float tsum = 0.f;
        unsigned plo[4], phi[4];            // packed bf16 P, j={0,1} / {2,3}
        #pragma unroll
        for (int n = 0; n < 4; ++n) {
            float p0 = __expf(sacc[n][0] - m);
            float p1 = __expf(sacc[n][1] - m);
            float p2 = __expf(sacc[n][2] - m);
            float p3 = __expf(sacc[n][3] - m);
            tsum += (p0 + p1) + (p2 + p3);
            plo[n] = pack_bf2(p0, p1);
            phi[n] = pack_bf2(p2, p3);
        }
        tsum += __shfl_xor(tsum, 16);
        tsum += __shfl_xor(tsum, 32);
        ssum = ssum * corr + tsum;
        #pragma unroll
        for (int n = 0; n < 8; ++n) {       // lane-local rescale (q = l16)
            #pragma unroll
            for (int j = 0; j < 4; ++j) oaccT[n][j] *= corr;
        }

        // ---- P redistribution in-register: B-frag[ks][i] =
        //      pq[2ks+(lg>>1)][i&3] from lane l16+16*((2lg+(i>>2))&3) ----
        const int sA = (((2 * lg)     & 3) << 4) | l16;
        const int sB = (((2 * lg + 1) & 3) << 4) | l16;
        const bool hi = (lg >= 2);
        bf16x8 pfragB[2];
        #pragma unroll
        for (int ks = 0; ks < 2; ++ks) {
            unsigned eA0 = __shfl(plo[2 * ks],     sA), eA1 = __shfl(phi[2 * ks],     sA);
            unsigned fA0 = __shfl(plo[2 * ks + 1], sA), fA1 = __shfl(phi[2 * ks + 1], sA);
            unsigned eB0 = __shfl(plo[2 * ks],     sB), eB1 = __shfl(phi[2 * ks],     sB);
            unsigned fB0 = __shfl(plo[2 * ks + 1], sB), fB1 = __shfl(phi[2 * ks + 1], sB);
            union { unsigned u[4]; bf16x8 v; } cv;
            cv.u[0] = hi ? fA0 : eA0;       // i = 0,1
            cv.u[1] = hi ? fA1 : eA1;       // i = 2,3
            cv.u[2] = hi ? fB0 : eB0;       // i = 4,5
            cv.u[3] = hi ? fB1 : eB1;       // i = 6,7
            pfragB[ks] = cv.v;
        }

        // ---- PV swapped: O^T[d][q] += V^T[d][kv] * P^T[kv][q] ----
        #pragma unroll
        for (int ks = 0; ks < 2; ++ks) {
            #pragma unroll
            for (int n = 0; n < 8; ++n) {
                bf16x8 vfrag = *(const bf16x8*)(smem + vswz(n * 16 + l16, ks * 64 + lg * 16));
                oaccT[n] = __builtin_amdgcn_mfma_f32_16x16x32_bf16(
                    vfrag, pfragB[ks], oaccT[n], 0, 0, 0);
            }
        }
        __syncthreads();
    }

    // ---- epilogue: per-wave LDS transpose -> coalesced float4 writes ----
    float* scr = (float*)(smem + w * 8192);     // 16 q-rows x 128 d
    const float inv = (MODE == 0) ? 1.0f / ssum : 1.0f;
    #pragma unroll
    for (int n = 0; n < 8; ++n) {
        #pragma unroll
        for (int j = 0; j < 4; ++j) {
            const int d = n * 16 + lg * 4 + j;
            scr[l16 * 128 + (d ^ ((l16 & 7) << 2))] = oaccT[n][j] * inv;
        }
    }
    asm volatile("s_waitcnt lgkmcnt(0)" ::: "memory");
    __builtin_amdgcn_sched_barrier(0);
    #pragma unroll
    for (int cc = 0; cc < 8; ++cc) {
        const int r  = cc * 2 + (l >> 5);
        const int dw = (l & 31) * 4;
        f32x4 val = *(f32x4*)&scr[r * 128 + (dw ^ ((r & 7) << 2))];
        const int qr = q0 + w * 16 + r;
        if (MODE == 0) {
            *(f32x4*)(out + ((size_t)b * S + qr) * (size_t)(H * D) + h * D + dw) = val;
        } else {
            *(f32x4*)(wsO + ((((size_t)z * B + b) * S + qr) * H + h) * (size_t)D + dw) = val;
        }
    }
    if (MODE == 1 && lg == 0)
        wsML[(((size_t)z * B + b) * S + qi) * H + h] = make_float2(m, ssum);
}

__global__ __launch_bounds__(256) void combine_kernel(
    const float* __restrict__ wsO, const float2* __restrict__ wsML,
    float* __restrict__ out)
{
    constexpr int R    = B * S * H;         // 16384 rows
    constexpr int TOT4 = R * D / 4;         // float4 elements
    for (int i4 = blockIdx.x * 256 + threadIdx.x; i4 < TOT4;
         i4 += gridDim.x * 256) {
        const int row = i4 >> 5;            // D/4 = 32 float4 per row
        float2 e[NS];
        float M = MNEG;
        #pragma unroll
        for (int cc = 0; cc < NS; ++cc) {
            e[cc] = wsML[(size_t)cc * R + row];
            M = fmaxf(M, e[cc].x);
        }
        float L = 0.f;
        float v0 = 0.f, v1 = 0.f, v2 = 0.f, v3 = 0.f;
        #pragma unroll
        for (int cc = 0; cc < NS; ++cc) {
            const float wgt = __expf(e[cc].x - M);
            L += e[cc].y * wgt;
            float4 tv = ((const float4*)wsO)[(size_t)cc * TOT4 + i4];
            v0 += tv.x * wgt; v1 += tv.y * wgt; v2 += tv.z * wgt; v3 += tv.w * wgt;
        }
        const float inv = 1.0f / L;
        ((float4*)out)[i4] = make_float4(v0 * inv, v1 * inv, v2 * inv, v3 * inv);
    }
}

extern "C" void kernel_launch(void* const* d_in, const int* in_sizes, int n_in,
                              void* d_out, int out_size, void* d_ws, size_t ws_size,
                              hipStream_t stream) {
    const float* q  = (const float*)d_in[0];
    const float* k  = (const float*)d_in[1];
    const float* v  = (const float*)d_in[2];
    const float* kc = (const float*)d_in[3];
    const float* vc = (const float*)d_in[4];
    const int*   ip = (const int*)d_in[5];
    float* out = (float*)d_out;

    const size_t nO  = (size_t)NS * B * S * H * D;
    const size_t nML = (size_t)NS * B * S * H;          // float2 elements
    const size_t need = (nO + 2 * nML) * sizeof(float);

    if (ws_size >= need) {
        float*  wsO  = (float*)d_ws;
        float2* wsML = (float2*)(wsO + nO);
        sdpa_kernel<1><<<dim3(B * H, S / QBLK, NS), 256, 0, stream>>>(
            q, k, v, kc, vc, ip, out, wsO, wsML);
        combine_kernel<<<2048, 256, 0, stream>>>(wsO, wsML, out);
    } else {
        sdpa_kernel<0><<<dim3(B * H, S / QBLK), 256, 0, stream>>>(
            q, k, v, kc, vc, ip, out, nullptr, nullptr);
    }
}